// Round 3
// baseline (374.303 us; speedup 1.0000x reference)
//
#include <hip/hip_runtime.h>
#include <math.h>

// ACT skip-RNN, H=O=4096, I=4095 (xin=[flag,x], len 4096).
// acc += 2*sigmoid(W_halt@s_new + 1.0); halts when acc >= 0.99 (step 1 for this data).
// Persistent plain-launch kernel + software grid barrier.
// R3: GRID=256 x TPB=1024 -> 16 waves/CU (was 4) to hide HBM latency.
// Co-residency proof: 1 block/CU; LDS 32KB<=160KB, 16 waves<=32, VGPR<=128 ok.

#define H      4096
#define GRID   256
#define TPB    1024
#define NWAVE  (TPB / 64)    // 16 waves per block
#define RPB    (H / GRID)    // 16 rows per block
#define NMAX   16
#define THRESH 0.99f         // 1.0 - EPS

// ws float layout: [0]=cnt [1]=gen [2..2+NMAX)=hdot[t] | [32..32+H)=sb0 | [32+H..32+2H)=sb1
// First 128 bytes zeroed via hipMemsetAsync before launch.

__device__ __forceinline__ float wave_reduce(float a) {
    #pragma unroll
    for (int off = 32; off > 0; off >>= 1) a += __shfl_down(a, off);
    return a;
}

__device__ __forceinline__ void grid_barrier(int* cnt, int* gen) {
    __syncthreads();
    if (threadIdx.x == 0) {
        __threadfence();  // release: publish this block's global writes
        int g = __hip_atomic_load(gen, __ATOMIC_RELAXED, __HIP_MEMORY_SCOPE_AGENT);
        int prev = __hip_atomic_fetch_add(cnt, 1, __ATOMIC_ACQ_REL, __HIP_MEMORY_SCOPE_AGENT);
        if (prev == GRID - 1) {
            __hip_atomic_store(cnt, 0, __ATOMIC_RELAXED, __HIP_MEMORY_SCOPE_AGENT);
            __hip_atomic_fetch_add(gen, 1, __ATOMIC_RELEASE, __HIP_MEMORY_SCOPE_AGENT);
        } else {
            while (__hip_atomic_load(gen, __ATOMIC_ACQUIRE, __HIP_MEMORY_SCOPE_AGENT) == g)
                __builtin_amdgcn_s_sleep(8);
        }
        __threadfence();  // acquire: fresh post-barrier reads
    }
    __syncthreads();
}

__global__ __launch_bounds__(TPB) void act_skip_rnn(
    const float* __restrict__ x,      const float* __restrict__ s0,
    const float* __restrict__ y0,     const float* __restrict__ h0,
    const float* __restrict__ W_ih,   const float* __restrict__ b_ih,
    const float* __restrict__ W_hh,   const float* __restrict__ b_hh,
    const float* __restrict__ W_halt, const float* __restrict__ b_halt,
    const float* __restrict__ W_out,  const float* __restrict__ b_out,
    float* __restrict__ out, float* ws)
{
    int*   cnt  = (int*)ws;
    int*   gen  = (int*)ws + 1;
    float* hdot = ws + 2;
    float* sb0  = ws + 32;
    float* sb1  = ws + 32 + H;

    const int tid  = threadIdx.x;
    const int bid  = blockIdx.x;
    const int wave = tid >> 6;     // 0..15
    const int lane = tid & 63;

    __shared__ float xl[H];   // xin (flag slot = 0; flag handled via W_ih col 0 at t==0)
    __shared__ float sl[H];   // current s

    // stage xin into LDS
    if (tid == 0) xl[0] = 0.f;
    for (int i = tid; i < H - 1; i += TPB) xl[i + 1] = x[i];

    const float h0v = h0[0];
    const float h0b = (h0v >= THRESH) ? 1.f : 0.f;   // binarize(h0)
    const float bh  = b_halt[0];

    float  acc      = h0v;
    float  last_acc = 0.f;
    int    ponder   = 0;
    bool   halted   = false;
    float* slast    = sb0;

    if (h0b == 0.f) {
        for (int t = 0; t < NMAX; ++t) {
            const float* scur = (t == 0) ? s0 : ((t & 1) ? sb0 : sb1);
            float*       snew = (t & 1) ? sb1 : sb0;

            // stage current s into LDS
            __syncthreads();
            for (int i = tid; i < H / 4; i += TPB)
                ((float4*)sl)[i] = ((const float4*)scur)[i];
            __syncthreads();

            // Phase A: one row per wave: s_new[row] = tanh(W_ih@xin + W_hh@s + b)
            const int row = bid * RPB + wave;
            const float4* wih = (const float4*)(W_ih + (size_t)row * H);
            const float4* whh = (const float4*)(W_hh + (size_t)row * H);
            float a0 = 0.f, a1 = 0.f;
            #pragma unroll
            for (int k = 0; k < 16; k += 2) {
                const int i0 = lane + (k << 6);
                const int i1 = lane + ((k + 1) << 6);
                float4 wa0 = wih[i0], wb0 = whh[i0];
                float4 wa1 = wih[i1], wb1 = whh[i1];
                float4 va0 = ((const float4*)xl)[i0], vb0 = ((const float4*)sl)[i0];
                float4 va1 = ((const float4*)xl)[i1], vb1 = ((const float4*)sl)[i1];
                a0 += wa0.x*va0.x + wa0.y*va0.y + wa0.z*va0.z + wa0.w*va0.w
                    + wb0.x*vb0.x + wb0.y*vb0.y + wb0.z*vb0.z + wb0.w*vb0.w;
                a1 += wa1.x*va1.x + wa1.y*va1.y + wa1.z*va1.z + wa1.w*va1.w
                    + wb1.x*vb1.x + wb1.y*vb1.y + wb1.z*vb1.z + wb1.w*vb1.w;
            }
            float a = wave_reduce(a0 + a1);
            if (lane == 0) {
                float z = a + b_ih[row] + b_hh[row];
                if (t == 0) z += W_ih[(size_t)row * H];  // xin[0]=1 on first step
                float sv = tanhf(z);
                snew[row] = sv;
                atomicAdd(&hdot[t], W_halt[row] * sv);
            }

            grid_barrier(cnt, gen);

            // uniform halt update (identical in every block)
            float hd = ((volatile float*)hdot)[t];
            float sg = 1.f / (1.f + expf(-(hd + bh)));
            acc += 2.f * sg;
            if (acc >= THRESH) { halted = true; last_acc = acc; slast = snew; break; }
            ponder++;
        }
    }

    // ---- epilogue ----
    if (h0b != 0.f) {
        for (int i = bid * TPB + tid; i < H; i += GRID * TPB) {
            out[i]     = y0[i];
            out[H + i] = s0[i];
        }
        if (bid == 0 && tid == 0) { out[2*H] = 0.f; out[2*H + 1] = h0v - 1.f; }
        return;
    }
    if (!halted) {  // ran all NMAX steps without halting: y_sel = s_sel = 0
        for (int i = bid * TPB + tid; i < H; i += GRID * TPB) {
            out[i]     = 0.f;
            out[H + i] = 0.f;
        }
        if (bid == 0 && tid == 0) { out[2*H] = (float)ponder; out[2*H + 1] = -1.f; }
        return;
    }

    // halted: y = W_out @ s_halt + b_out  (one row per wave)
    __syncthreads();
    for (int i = tid; i < H / 4; i += TPB)
        ((float4*)sl)[i] = ((const float4*)slast)[i];
    __syncthreads();

    {
        const int row = bid * RPB + wave;
        const float4* wo = (const float4*)(W_out + (size_t)row * H);
        float a0 = 0.f, a1 = 0.f;
        #pragma unroll
        for (int k = 0; k < 16; k += 2) {
            const int i0 = lane + (k << 6);
            const int i1 = lane + ((k + 1) << 6);
            float4 w0 = wo[i0], w1 = wo[i1];
            float4 s4_0 = ((const float4*)sl)[i0], s4_1 = ((const float4*)sl)[i1];
            a0 += w0.x*s4_0.x + w0.y*s4_0.y + w0.z*s4_0.z + w0.w*s4_0.w;
            a1 += w1.x*s4_1.x + w1.y*s4_1.y + w1.z*s4_1.z + w1.w*s4_1.w;
        }
        float a = wave_reduce(a0 + a1);
        if (lane == 0) {
            out[row]     = a + b_out[row];
            out[H + row] = sl[row];
        }
    }
    if (bid == 0 && tid == 0) {
        out[2*H]     = (float)ponder;
        out[2*H + 1] = last_acc - 1.f;
    }
}

extern "C" void kernel_launch(void* const* d_in, const int* in_sizes, int n_in,
                              void* d_out, int out_size, void* d_ws, size_t ws_size,
                              hipStream_t stream) {
    const float* x      = (const float*)d_in[0];
    const float* s0     = (const float*)d_in[1];
    const float* y0     = (const float*)d_in[2];
    const float* h0     = (const float*)d_in[3];
    const float* W_ih   = (const float*)d_in[4];
    const float* b_ih   = (const float*)d_in[5];
    const float* W_hh   = (const float*)d_in[6];
    const float* b_hh   = (const float*)d_in[7];
    const float* W_halt = (const float*)d_in[8];
    const float* b_halt = (const float*)d_in[9];
    const float* W_out  = (const float*)d_in[10];
    const float* b_out  = (const float*)d_in[11];
    float* out = (float*)d_out;
    float* ws  = (float*)d_ws;   // needs (32 + 2*4096)*4 B ≈ 33 KB

    // zero barrier counters + hdot slots (ws is poisoned 0xAA before every call)
    hipMemsetAsync(ws, 0, 128, stream);

    act_skip_rnn<<<dim3(GRID), dim3(TPB), 0, stream>>>(
        x, s0, y0, h0, W_ih, b_ih, W_hh, b_hh,
        W_halt, b_halt, W_out, b_out, out, ws);
}

// Round 4
// 366.869 us; speedup vs baseline: 1.0203x; 1.0203x over previous
//
#include <hip/hip_runtime.h>
#include <math.h>

// ACT skip-RNN, H=O=4096, I=4095 (xin=[flag,x], len 4096).
// R4: decomposed into 3 dispatches. Hot path (halts at step 0, true for this
// data) runs barrier-free: K1 (W_ih/W_hh matvec + halt decision via ticket
// atomic), K_rest (early-exit unless not-halted; persistent rare path),
// K2 (W_out matvec + epilogue). Cross-kernel visibility via dispatch boundary.
//
// ws float layout: [0]=cnt [1]=gen [2]=ndone [3]=pad
//   [4]=halted(int) [5]=sel(int) [6]=ponder(int) [7]=acc [8]=last_acc
//   [16..32)=hdot[16]  [32..32+H)=sb0  [32+H..32+2H)=sb1
// First 128 B zeroed by hipMemsetAsync.

#define H      4096
#define NMAX   16
#define THRESH 0.99f         // 1.0 - EPS

__device__ __forceinline__ float wave_reduce(float a) {
    #pragma unroll
    for (int off = 32; off > 0; off >>= 1) a += __shfl_down(a, off);
    return a;
}

// ---------------- K1: step 0 (s1 = tanh(W_ih@x1 + W_hh@s0 + b)) ----------------
// 1024 blocks x 256 thr (4 waves), 1 row/wave. No grid barrier.
__global__ __launch_bounds__(256, 4) void k_step0(
    const float* __restrict__ x,      const float* __restrict__ s0,
    const float* __restrict__ h0,
    const float* __restrict__ W_ih,   const float* __restrict__ b_ih,
    const float* __restrict__ W_hh,   const float* __restrict__ b_hh,
    const float* __restrict__ W_halt, const float* __restrict__ b_halt,
    float* ws)
{
    if (h0[0] >= THRESH) return;   // ACT loop never executes

    __shared__ float xl[H];
    __shared__ float sl[H];
    const int tid = threadIdx.x, bid = blockIdx.x;
    const int wave = tid >> 6, lane = tid & 63;

    if (tid == 0) xl[0] = 0.f;     // flag slot; t==0 flag handled via W_ih col 0
    for (int i = tid; i < H - 1; i += 256) xl[i + 1] = x[i];
    for (int i = tid; i < H / 4; i += 256)
        ((float4*)sl)[i] = ((const float4*)s0)[i];
    __syncthreads();

    const int row = bid * 4 + wave;
    const float4* wih = (const float4*)(W_ih + (size_t)row * H);
    const float4* whh = (const float4*)(W_hh + (size_t)row * H);
    const float4* xv  = (const float4*)xl;
    const float4* sv  = (const float4*)sl;
    float a0 = 0.f, a1 = 0.f;
    #pragma unroll 4
    for (int k = 0; k < 16; ++k) {
        const int idx = lane + (k << 6);          // lane-contiguous float4
        float4 wa = wih[idx], wb = whh[idx];
        float4 va = xv[idx],  vb = sv[idx];
        a0 += wa.x*va.x + wa.y*va.y + wa.z*va.z + wa.w*va.w;
        a1 += wb.x*vb.x + wb.y*vb.y + wb.z*vb.z + wb.w*vb.w;
    }
    float a = wave_reduce(a0 + a1);

    if (lane == 0) {
        float z = a + b_ih[row] + b_hh[row] + W_ih[(size_t)row * H]; // xin[0]=1
        float s1 = tanhf(z);
        ws[32 + row] = s1;                         // sb0 = s1 (plain store; K2/K_rest see it via dispatch boundary)
        atomicAdd(&ws[16], W_halt[row] * s1);      // hdot[0]

        // ticket: last of 4096 waves computes the halt decision
        int prev = __hip_atomic_fetch_add((int*)ws + 2, 1,
                     __ATOMIC_ACQ_REL, __HIP_MEMORY_SCOPE_AGENT);
        if (prev == 4096 - 1) {
            float hd = __hip_atomic_load(&ws[16], __ATOMIC_RELAXED,
                                         __HIP_MEMORY_SCOPE_AGENT);
            float sg  = 1.f / (1.f + expf(-(hd + b_halt[0])));
            float acc = h0[0] + 2.f * sg;
            int*  wsI = (int*)ws;
            int halted = (acc >= THRESH) ? 1 : 0;
            wsI[4] = halted;
            wsI[5] = 0;                 // s_halt (if halted) lives in sb0
            wsI[6] = halted ? 0 : 1;    // ponder after step 0
            ws[7]  = acc;
            ws[8]  = acc;               // last_acc (used only if halted)
        }
    }
}

// ---------------- K_rest: rare path, steps 1..15 (persistent + grid barrier) ----
#define RG   256   // blocks (1 per CU -> co-resident; spin barrier safe)
#define RT   256   // threads (4 waves), 16 rows/block, 4 rows/wave

__device__ __forceinline__ void grid_barrier(int* cnt, int* gen) {
    __syncthreads();
    if (threadIdx.x == 0) {
        __threadfence();
        int g = __hip_atomic_load(gen, __ATOMIC_RELAXED, __HIP_MEMORY_SCOPE_AGENT);
        int prev = __hip_atomic_fetch_add(cnt, 1, __ATOMIC_ACQ_REL, __HIP_MEMORY_SCOPE_AGENT);
        if (prev == RG - 1) {
            __hip_atomic_store(cnt, 0, __ATOMIC_RELAXED, __HIP_MEMORY_SCOPE_AGENT);
            __hip_atomic_fetch_add(gen, 1, __ATOMIC_RELEASE, __HIP_MEMORY_SCOPE_AGENT);
        } else {
            while (__hip_atomic_load(gen, __ATOMIC_ACQUIRE, __HIP_MEMORY_SCOPE_AGENT) == g)
                __builtin_amdgcn_s_sleep(8);
        }
        __threadfence();
    }
    __syncthreads();
}

__global__ __launch_bounds__(RT) void k_rest(
    const float* __restrict__ x,
    const float* __restrict__ h0,
    const float* __restrict__ W_ih,   const float* __restrict__ b_ih,
    const float* __restrict__ W_hh,   const float* __restrict__ b_hh,
    const float* __restrict__ W_halt, const float* __restrict__ b_halt,
    float* ws)
{
    int* wsI = (int*)ws;
    if (h0[0] >= THRESH) return;     // no steps ran at all
    if (wsI[4]) return;              // halted at step 0 (common case): ~no-op

    float* hdot = ws + 16;
    float* sb0  = ws + 32;
    float* sb1  = ws + 32 + H;

    const int tid = threadIdx.x, bid = blockIdx.x;
    const int wave = tid >> 6, lane = tid & 63;

    __shared__ float xl[H];
    __shared__ float sl[H];
    if (tid == 0) xl[0] = 0.f;       // flag = 0 for all t >= 1
    for (int i = tid; i < H - 1; i += RT) xl[i + 1] = x[i];

    float acc    = ws[7];
    int   ponder = wsI[6];
    const float bh = b_halt[0];
    bool  halted = false;
    int   sel = 0;
    float last_acc = 0.f;

    for (int t = 1; t < NMAX; ++t) {
        const float* scur = (t & 1) ? sb0 : sb1;   // s_t
        float*       snew = (t & 1) ? sb1 : sb0;

        __syncthreads();
        for (int i = tid; i < H / 4; i += RT)
            ((float4*)sl)[i] = ((const float4*)scur)[i];
        __syncthreads();

        for (int r = 0; r < 4; ++r) {
            const int row = bid * 16 + r * 4 + wave;
            const float4* wih = (const float4*)(W_ih + (size_t)row * H);
            const float4* whh = (const float4*)(W_hh + (size_t)row * H);
            float a0 = 0.f, a1 = 0.f;
            #pragma unroll 4
            for (int k = 0; k < 16; ++k) {
                const int idx = lane + (k << 6);
                float4 wa = wih[idx], wb = whh[idx];
                float4 va = ((const float4*)xl)[idx], vb = ((const float4*)sl)[idx];
                a0 += wa.x*va.x + wa.y*va.y + wa.z*va.z + wa.w*va.w;
                a1 += wb.x*vb.x + wb.y*vb.y + wb.z*vb.z + wb.w*vb.w;
            }
            float a = wave_reduce(a0 + a1);
            if (lane == 0) {
                float sv = tanhf(a + b_ih[row] + b_hh[row]);
                snew[row] = sv;
                atomicAdd(&hdot[t], W_halt[row] * sv);
            }
        }

        grid_barrier((int*)ws, (int*)ws + 1);

        float hd = ((volatile float*)hdot)[t];
        float sg = 1.f / (1.f + expf(-(hd + bh)));
        acc += 2.f * sg;
        if (acc >= THRESH) { halted = true; last_acc = acc; sel = (t & 1) ? 1 : 0; break; }
        ponder++;
    }

    if (bid == 0 && tid == 0) {
        wsI[4] = halted ? 1 : 0;
        wsI[5] = sel;
        wsI[6] = ponder;
        ws[8]  = last_acc;
    }
}

// ---------------- K2: output (y = W_out@s_halt + b_out) + epilogue --------------
__global__ __launch_bounds__(256, 4) void k_out(
    const float* __restrict__ s0,    const float* __restrict__ y0,
    const float* __restrict__ h0,
    const float* __restrict__ W_out, const float* __restrict__ b_out,
    const float* __restrict__ ws, float* __restrict__ out)
{
    const float h0v = h0[0];
    const int tid = threadIdx.x, bid = blockIdx.x;

    if (h0v >= THRESH) {             // binarize(h0)==1: pass-through
        for (int i = bid * 256 + tid; i < H; i += 1024 * 256) {
            out[i]     = y0[i];
            out[H + i] = s0[i];
        }
        if (bid == 0 && tid == 0) { out[2*H] = 0.f; out[2*H + 1] = h0v - 1.f; }
        return;
    }

    const int* wsI = (const int*)ws;
    if (!wsI[4]) {                   // never halted within NMAX steps
        for (int i = bid * 256 + tid; i < H; i += 1024 * 256) {
            out[i]     = 0.f;
            out[H + i] = 0.f;
        }
        if (bid == 0 && tid == 0) { out[2*H] = (float)wsI[6]; out[2*H + 1] = -1.f; }
        return;
    }

    const float* sfin = ws + 32 + (wsI[5] ? H : 0);
    __shared__ float sl[H];
    for (int i = tid; i < H / 4; i += 256)
        ((float4*)sl)[i] = ((const float4*)sfin)[i];
    __syncthreads();

    const int wave = tid >> 6, lane = tid & 63;
    const int row = bid * 4 + wave;
    const float4* wo = (const float4*)(W_out + (size_t)row * H);
    const float4* sv = (const float4*)sl;
    float a0 = 0.f, a1 = 0.f;
    #pragma unroll 4
    for (int k = 0; k < 16; k += 2) {
        const int i0 = lane + (k << 6), i1 = lane + ((k + 1) << 6);
        float4 w0 = wo[i0], w1 = wo[i1];
        float4 v0 = sv[i0], v1 = sv[i1];
        a0 += w0.x*v0.x + w0.y*v0.y + w0.z*v0.z + w0.w*v0.w;
        a1 += w1.x*v1.x + w1.y*v1.y + w1.z*v1.z + w1.w*v1.w;
    }
    float a = wave_reduce(a0 + a1);
    if (lane == 0) {
        out[row]     = a + b_out[row];
        out[H + row] = sl[row];
    }
    if (bid == 0 && tid == 0) {
        out[2*H]     = (float)wsI[6];
        out[2*H + 1] = ws[8] - 1.f;
    }
}

extern "C" void kernel_launch(void* const* d_in, const int* in_sizes, int n_in,
                              void* d_out, int out_size, void* d_ws, size_t ws_size,
                              hipStream_t stream) {
    const float* x      = (const float*)d_in[0];
    const float* s0     = (const float*)d_in[1];
    const float* y0     = (const float*)d_in[2];
    const float* h0     = (const float*)d_in[3];
    const float* W_ih   = (const float*)d_in[4];
    const float* b_ih   = (const float*)d_in[5];
    const float* W_hh   = (const float*)d_in[6];
    const float* b_hh   = (const float*)d_in[7];
    const float* W_halt = (const float*)d_in[8];
    const float* b_halt = (const float*)d_in[9];
    const float* W_out  = (const float*)d_in[10];
    const float* b_out  = (const float*)d_in[11];
    float* out = (float*)d_out;
    float* ws  = (float*)d_ws;   // needs (32 + 2*4096)*4 B ≈ 33 KB

    hipMemsetAsync(ws, 0, 128, stream);   // cnt/gen/ndone/state/hdot

    k_step0<<<dim3(1024), dim3(256), 0, stream>>>(
        x, s0, h0, W_ih, b_ih, W_hh, b_hh, W_halt, b_halt, ws);
    k_rest<<<dim3(RG), dim3(RT), 0, stream>>>(
        x, h0, W_ih, b_ih, W_hh, b_hh, W_halt, b_halt, ws);
    k_out<<<dim3(1024), dim3(256), 0, stream>>>(
        s0, y0, h0, W_out, b_out, ws, out);
}

// Round 5
// 231.381 us; speedup vs baseline: 1.6177x; 1.5856x over previous
//
#include <hip/hip_runtime.h>
#include <math.h>

// ACT skip-RNN, H=O=4096, I=4095 (xin=[flag,x], len 4096).
// R5: hot path has ZERO same-address atomics and no LDS staging.
//   k_prep  : zero ws control words + stage aligned xin into out-scratch
//   k_step0 : s1 = tanh(W_ih@x1 + W_hh@s0 + b); per-block halt partial -> out[bid]
//   k_halt  : reduce 2048 partials, write halt decision
//   k_rest  : rare path (steps 1..15), persistent + grid barrier, early-exits
//   k_out   : y = W_out@s_halt + b_out, epilogue (overwrites all of d_out)
// d_out scratch use: out[0..2048)=hpartial, out[2048..6144)=xin_aligned;
// both fully dead by the time k_out rewrites d_out. ws stays 33 KB.
//
// ws float layout: [0]=cnt [1]=gen [4]=halted [5]=sel [6]=ponder [7]=acc
//   [8]=last_acc [16..32)=hdot[16] [32..32+H)=sb0 [32+H..32+2H)=sb1

#define H      4096
#define NMAX   16
#define THRESH 0.99f         // 1.0 - EPS

__device__ __forceinline__ float wave_reduce(float a) {
    #pragma unroll
    for (int off = 32; off > 0; off >>= 1) a += __shfl_down(a, off);
    return a;
}

// ---------------- k_prep: control-word zero + aligned xin staging ----------------
__global__ __launch_bounds__(256) void k_prep(
    const float* __restrict__ x, float* __restrict__ ws, float* __restrict__ out)
{
    const int i = blockIdx.x * 256 + threadIdx.x;
    if (i < 32) ws[i] = 0.f;               // cnt/gen/halted/sel/ponder/acc/hdot
    if (i == 0) out[2048] = 0.f;           // xin[0] = flag slot (0; t==0 flag via W col 0)
    if (i < H - 1) out[2048 + 1 + i] = x[i];
}

// ---------------- k_step0: step-0 matvec, no atomics ----------------
// 2048 blocks x 256 thr, 8 blocks/CU -> 32 waves/CU. 2 rows/block, half-row/wave.
__global__ __launch_bounds__(256, 8) void k_step0(
    const float* __restrict__ s0,     const float* __restrict__ h0,
    const float* __restrict__ W_ih,   const float* __restrict__ b_ih,
    const float* __restrict__ W_hh,   const float* __restrict__ b_hh,
    const float* __restrict__ W_halt,
    float* __restrict__ ws, float* __restrict__ out)
{
    if (h0[0] >= THRESH) return;           // ACT loop never executes

    const int tid  = threadIdx.x, bid = blockIdx.x;
    const int wave = tid >> 6,   lane = tid & 63;
    const int row  = bid * 2 + (wave >> 1);
    const int half = wave & 1;

    const float4* wih = (const float4*)(W_ih + (size_t)row * H);
    const float4* whh = (const float4*)(W_hh + (size_t)row * H);
    const float4* xv  = (const float4*)(out + 2048);   // aligned xin (L2/L3-resident)
    const float4* sv  = (const float4*)s0;

    const int base = half * 512 + lane;    // this wave's half-row, lane-contiguous
    float a0 = 0.f, a1 = 0.f;
    #pragma unroll
    for (int k = 0; k < 8; ++k) {
        const int idx = base + (k << 6);
        float4 w0 = wih[idx], v0 = xv[idx];
        float4 w1 = whh[idx], v1 = sv[idx];
        a0 += w0.x*v0.x + w0.y*v0.y + w0.z*v0.z + w0.w*v0.w;
        a1 += w1.x*v1.x + w1.y*v1.y + w1.z*v1.z + w1.w*v1.w;
    }
    float a = wave_reduce(a0 + a1);

    __shared__ float part[4];
    if (lane == 0) part[wave] = a;
    __syncthreads();
    if (tid == 0) {
        const int r0 = bid * 2, r1 = r0 + 1;
        float z0 = part[0] + part[1] + b_ih[r0] + b_hh[r0] + W_ih[(size_t)r0 * H];
        float z1 = part[2] + part[3] + b_ih[r1] + b_hh[r1] + W_ih[(size_t)r1 * H];
        float s1a = tanhf(z0), s1b = tanhf(z1);
        ws[32 + r0] = s1a;                 // sb0 = s1
        ws[32 + r1] = s1b;
        out[bid] = W_halt[r0] * s1a + W_halt[r1] * s1b;   // private slot: no contention
    }
}

// ---------------- k_halt: reduce partials, halt decision ----------------
__global__ __launch_bounds__(256) void k_halt(
    const float* __restrict__ h0, const float* __restrict__ b_halt,
    const float* __restrict__ hp, float* ws)
{
    if (h0[0] >= THRESH) return;
    const int tid = threadIdx.x;
    const float4* h4 = (const float4*)hp;  // out[0..2048) as 512 float4
    float a = 0.f;
    for (int i = tid; i < 512; i += 256) { float4 v = h4[i]; a += v.x + v.y + v.z + v.w; }
    a = wave_reduce(a);
    __shared__ float part[4];
    if ((tid & 63) == 0) part[tid >> 6] = a;
    __syncthreads();
    if (tid == 0) {
        float hd  = part[0] + part[1] + part[2] + part[3];
        float sg  = 1.f / (1.f + expf(-(hd + b_halt[0])));
        float acc = h0[0] + 2.f * sg;
        int*  wsI = (int*)ws;
        int halted = (acc >= THRESH) ? 1 : 0;
        wsI[4] = halted;
        wsI[5] = 0;                        // s_halt (if halted) is sb0
        wsI[6] = halted ? 0 : 1;           // ponder after step 0
        ws[7]  = acc;
        ws[8]  = acc;                      // last_acc if halted
    }
}

// ---------------- k_rest: rare path, steps 1..15 (persistent + grid barrier) ----
#define RG   256
#define RT   256

__device__ __forceinline__ void grid_barrier(int* cnt, int* gen) {
    __syncthreads();
    if (threadIdx.x == 0) {
        __threadfence();
        int g = __hip_atomic_load(gen, __ATOMIC_RELAXED, __HIP_MEMORY_SCOPE_AGENT);
        int prev = __hip_atomic_fetch_add(cnt, 1, __ATOMIC_ACQ_REL, __HIP_MEMORY_SCOPE_AGENT);
        if (prev == RG - 1) {
            __hip_atomic_store(cnt, 0, __ATOMIC_RELAXED, __HIP_MEMORY_SCOPE_AGENT);
            __hip_atomic_fetch_add(gen, 1, __ATOMIC_RELEASE, __HIP_MEMORY_SCOPE_AGENT);
        } else {
            while (__hip_atomic_load(gen, __ATOMIC_ACQUIRE, __HIP_MEMORY_SCOPE_AGENT) == g)
                __builtin_amdgcn_s_sleep(8);
        }
        __threadfence();
    }
    __syncthreads();
}

__global__ __launch_bounds__(RT) void k_rest(
    const float* __restrict__ x,
    const float* __restrict__ h0,
    const float* __restrict__ W_ih,   const float* __restrict__ b_ih,
    const float* __restrict__ W_hh,   const float* __restrict__ b_hh,
    const float* __restrict__ W_halt, const float* __restrict__ b_halt,
    float* ws)
{
    int* wsI = (int*)ws;
    if (h0[0] >= THRESH) return;     // no steps ran at all
    if (wsI[4]) return;              // halted at step 0 (common case): ~no-op

    float* hdot = ws + 16;
    float* sb0  = ws + 32;
    float* sb1  = ws + 32 + H;

    const int tid = threadIdx.x, bid = blockIdx.x;
    const int wave = tid >> 6, lane = tid & 63;

    __shared__ float xl[H];
    __shared__ float sl[H];
    if (tid == 0) xl[0] = 0.f;       // flag = 0 for all t >= 1
    for (int i = tid; i < H - 1; i += RT) xl[i + 1] = x[i];

    float acc    = ws[7];
    int   ponder = wsI[6];
    const float bh = b_halt[0];
    bool  halted = false;
    int   sel = 0;
    float last_acc = 0.f;

    for (int t = 1; t < NMAX; ++t) {
        const float* scur = (t & 1) ? sb0 : sb1;
        float*       snew = (t & 1) ? sb1 : sb0;

        __syncthreads();
        for (int i = tid; i < H / 4; i += RT)
            ((float4*)sl)[i] = ((const float4*)scur)[i];
        __syncthreads();

        for (int r = 0; r < 4; ++r) {
            const int row = bid * 16 + r * 4 + wave;
            const float4* wih = (const float4*)(W_ih + (size_t)row * H);
            const float4* whh = (const float4*)(W_hh + (size_t)row * H);
            float a0 = 0.f, a1 = 0.f;
            #pragma unroll 4
            for (int k = 0; k < 16; ++k) {
                const int idx = lane + (k << 6);
                float4 wa = wih[idx], wb = whh[idx];
                float4 va = ((const float4*)xl)[idx], vb = ((const float4*)sl)[idx];
                a0 += wa.x*va.x + wa.y*va.y + wa.z*va.z + wa.w*va.w;
                a1 += wb.x*vb.x + wb.y*vb.y + wb.z*vb.z + wb.w*vb.w;
            }
            float a = wave_reduce(a0 + a1);
            if (lane == 0) {
                float sv = tanhf(a + b_ih[row] + b_hh[row]);
                snew[row] = sv;
                atomicAdd(&hdot[t], W_halt[row] * sv);   // rare path: contention OK
            }
        }

        grid_barrier((int*)ws, (int*)ws + 1);

        float hd = ((volatile float*)hdot)[t];
        float sg = 1.f / (1.f + expf(-(hd + bh)));
        acc += 2.f * sg;
        if (acc >= THRESH) { halted = true; last_acc = acc; sel = (t & 1) ? 1 : 0; break; }
        ponder++;
    }

    if (bid == 0 && tid == 0) {
        wsI[4] = halted ? 1 : 0;
        wsI[5] = sel;
        wsI[6] = ponder;
        ws[8]  = last_acc;
    }
}

// ---------------- k_out: output matvec + epilogue ----------------
// 2048 blocks x 256 thr, 8 blocks/CU. 2 rows/block, half-row/wave. No atomics.
__global__ __launch_bounds__(256, 8) void k_out(
    const float* __restrict__ s0,    const float* __restrict__ y0,
    const float* __restrict__ h0,
    const float* __restrict__ W_out, const float* __restrict__ b_out,
    const float* __restrict__ ws, float* __restrict__ out)
{
    const float h0v = h0[0];
    const int tid = threadIdx.x, bid = blockIdx.x;

    if (h0v >= THRESH) {             // binarize(h0)==1: pass-through
        for (int i = bid * 256 + tid; i < H; i += 2048 * 256) {
            out[i]     = y0[i];
            out[H + i] = s0[i];
        }
        if (bid == 0 && tid == 0) { out[2*H] = 0.f; out[2*H + 1] = h0v - 1.f; }
        return;
    }

    const int* wsI = (const int*)ws;
    if (!wsI[4]) {                   // never halted within NMAX steps
        for (int i = bid * 256 + tid; i < H; i += 2048 * 256) {
            out[i]     = 0.f;
            out[H + i] = 0.f;
        }
        if (bid == 0 && tid == 0) { out[2*H] = (float)wsI[6]; out[2*H + 1] = -1.f; }
        return;
    }

    const float* sfin = ws + 32 + (wsI[5] ? H : 0);
    const int wave = tid >> 6, lane = tid & 63;
    const int row  = bid * 2 + (wave >> 1);
    const int half = wave & 1;

    const float4* wo = (const float4*)(W_out + (size_t)row * H);
    const float4* sv = (const float4*)sfin;
    const int base = half * 512 + lane;
    float a0 = 0.f, a1 = 0.f;
    #pragma unroll
    for (int k = 0; k < 8; k += 2) {
        const int i0 = base + (k << 6), i1 = base + ((k + 1) << 6);
        float4 w0 = wo[i0], v0 = sv[i0];
        float4 w1 = wo[i1], v1 = sv[i1];
        a0 += w0.x*v0.x + w0.y*v0.y + w0.z*v0.z + w0.w*v0.w;
        a1 += w1.x*v1.x + w1.y*v1.y + w1.z*v1.z + w1.w*v1.w;
    }
    float a = wave_reduce(a0 + a1);

    __shared__ float part[4];
    if (lane == 0) part[wave] = a;
    __syncthreads();
    if (tid == 0) {
        const int r0 = bid * 2, r1 = r0 + 1;
        out[r0]     = part[0] + part[1] + b_out[r0];
        out[r1]     = part[2] + part[3] + b_out[r1];
        out[H + r0] = sfin[r0];
        out[H + r1] = sfin[r1];
        if (bid == 0) {
            out[2*H]     = (float)wsI[6];
            out[2*H + 1] = ws[8] - 1.f;
        }
    }
}

extern "C" void kernel_launch(void* const* d_in, const int* in_sizes, int n_in,
                              void* d_out, int out_size, void* d_ws, size_t ws_size,
                              hipStream_t stream) {
    const float* x      = (const float*)d_in[0];
    const float* s0     = (const float*)d_in[1];
    const float* y0     = (const float*)d_in[2];
    const float* h0     = (const float*)d_in[3];
    const float* W_ih   = (const float*)d_in[4];
    const float* b_ih   = (const float*)d_in[5];
    const float* W_hh   = (const float*)d_in[6];
    const float* b_hh   = (const float*)d_in[7];
    const float* W_halt = (const float*)d_in[8];
    const float* b_halt = (const float*)d_in[9];
    const float* W_out  = (const float*)d_in[10];
    const float* b_out  = (const float*)d_in[11];
    float* out = (float*)d_out;
    float* ws  = (float*)d_ws;   // (32 + 2*4096)*4 B ≈ 33 KB used

    k_prep<<<dim3(16),   dim3(256), 0, stream>>>(x, ws, out);
    k_step0<<<dim3(2048), dim3(256), 0, stream>>>(
        s0, h0, W_ih, b_ih, W_hh, b_hh, W_halt, ws, out);
    k_halt<<<dim3(1),    dim3(256), 0, stream>>>(h0, b_halt, out, ws);
    k_rest<<<dim3(RG),   dim3(RT),  0, stream>>>(
        x, h0, W_ih, b_ih, W_hh, b_hh, W_halt, b_halt, ws);
    k_out<<<dim3(2048),  dim3(256), 0, stream>>>(
        s0, y0, h0, W_out, b_out, ws, out);
}

// Round 6
// 224.423 us; speedup vs baseline: 1.6678x; 1.0310x over previous
//
#include <hip/hip_runtime.h>
#include <math.h>

// ACT skip-RNN, H=O=4096, I=4095 (xin=[flag,x], len 4096).
// R6: matvec kernels rebuilt for MLP: __launch_bounds__(256,4) (128-VGPR
// budget), 1 full row/wave, explicit P-deep float4 prefetch on the weight
// stream(s), vectors staged in LDS (lgkmcnt path, vmcnt reserved for weights).
// Hot path still has zero same-address atomics (R5's win).
//   k_prep  : zero ws control words + stage aligned xin into out-scratch
//   k_step0 : s1 = tanh(W_ih@x1 + W_hh@s0 + b); per-block halt partial -> out[bid]
//   k_halt  : reduce 1024 partials, write halt decision
//   k_rest  : rare path (steps 1..15), persistent + grid barrier, early-exits
//   k_out   : y = W_out@s_halt + b_out, epilogue (overwrites all of d_out)
// d_out scratch: out[0..1024)=hpartial, out[2048..6144)=xin; dead before k_out.
// ws float layout: [0]=cnt [1]=gen [4]=halted [5]=sel [6]=ponder [7]=acc
//   [8]=last_acc [16..32)=hdot[16] [32..32+H)=sb0 [32+H..32+2H)=sb1

#define H      4096
#define NMAX   16
#define THRESH 0.99f         // 1.0 - EPS

__device__ __forceinline__ float wave_reduce(float a) {
    #pragma unroll
    for (int off = 32; off > 0; off >>= 1) a += __shfl_down(a, off);
    return a;
}

// ---------------- k_prep: control-word zero + aligned xin staging ----------------
__global__ __launch_bounds__(256) void k_prep(
    const float* __restrict__ x, float* __restrict__ ws, float* __restrict__ out)
{
    const int i = blockIdx.x * 256 + threadIdx.x;
    if (i < 32) ws[i] = 0.f;               // cnt/gen/halted/sel/ponder/acc/hdot
    if (i == 0) out[2048] = 0.f;           // xin[0] flag slot (t==0 flag via W col 0)
    if (i < H - 1) out[2048 + 1 + i] = x[i];
}

// ---------------- k_step0: step-0 matvec, P=4 pipelined, no atomics -------------
// 1024 blocks x 256 thr, 4 blocks/CU -> 16 waves/CU, 128-VGPR budget.
// 4 rows/block, 1 full row/wave; 2 weight streams, 2*P float4 in flight.
#define P0 4
__global__ __launch_bounds__(256, 4) void k_step0(
    const float* __restrict__ s0,     const float* __restrict__ h0,
    const float* __restrict__ W_ih,   const float* __restrict__ b_ih,
    const float* __restrict__ W_hh,   const float* __restrict__ b_hh,
    const float* __restrict__ W_halt,
    float* __restrict__ ws, float* __restrict__ out)
{
    if (h0[0] >= THRESH) return;           // ACT loop never executes

    const int tid  = threadIdx.x, bid = blockIdx.x;
    const int wave = tid >> 6,   lane = tid & 63;

    __shared__ float xl[H];
    __shared__ float sl[H];
    {   // stage vectors once per block: 4 float4 per thread per vector
        const float4* xg = (const float4*)(out + 2048);
        const float4* sg = (const float4*)s0;
        #pragma unroll
        for (int i = 0; i < 4; ++i) {
            ((float4*)xl)[tid + (i << 8)] = xg[tid + (i << 8)];
            ((float4*)sl)[tid + (i << 8)] = sg[tid + (i << 8)];
        }
    }
    __syncthreads();

    const int row = bid * 4 + wave;
    const float4* wih = (const float4*)(W_ih + (size_t)row * H);
    const float4* whh = (const float4*)(W_hh + (size_t)row * H);
    const float4* xv  = (const float4*)xl;
    const float4* sv  = (const float4*)sl;

    float4 wa[P0], wb[P0];                 // prefetch pipeline: 2*P0 loads in flight
    #pragma unroll
    for (int p = 0; p < P0; ++p) {
        wa[p] = wih[lane + (p << 6)];
        wb[p] = whh[lane + (p << 6)];
    }
    float a0 = 0.f, a1 = 0.f, a2 = 0.f, a3 = 0.f;
    #pragma unroll
    for (int k = 0; k < 16; ++k) {
        const int s = k & (P0 - 1);
        float4 cwa = wa[s], cwb = wb[s];
        const int kp = k + P0;
        if (kp < 16) {                     // compile-time guard (full unroll)
            wa[s] = wih[lane + (kp << 6)];
            wb[s] = whh[lane + (kp << 6)];
        }
        float4 va = xv[lane + (k << 6)], vb = sv[lane + (k << 6)];
        a0 += cwa.x*va.x + cwa.y*va.y;
        a1 += cwa.z*va.z + cwa.w*va.w;
        a2 += cwb.x*vb.x + cwb.y*vb.y;
        a3 += cwb.z*vb.z + cwb.w*vb.w;
    }
    float a = wave_reduce((a0 + a1) + (a2 + a3));

    __shared__ float hp[4];
    if (lane == 0) {
        float z  = a + b_ih[row] + b_hh[row] + W_ih[(size_t)row * H]; // xin[0]=1
        float s1 = tanhf(z);
        ws[32 + row] = s1;                 // sb0 = s1
        hp[wave] = W_halt[row] * s1;
    }
    __syncthreads();
    if (tid == 0) out[bid] = hp[0] + hp[1] + hp[2] + hp[3];   // private slot
}

// ---------------- k_halt: reduce 1024 partials, halt decision ----------------
__global__ __launch_bounds__(256) void k_halt(
    const float* __restrict__ h0, const float* __restrict__ b_halt,
    const float* __restrict__ hp, float* ws)
{
    if (h0[0] >= THRESH) return;
    const int tid = threadIdx.x;
    const float4* h4 = (const float4*)hp;  // out[0..1024) as 256 float4
    float4 v = h4[tid];
    float a = wave_reduce(v.x + v.y + v.z + v.w);
    __shared__ float part[4];
    if ((tid & 63) == 0) part[tid >> 6] = a;
    __syncthreads();
    if (tid == 0) {
        float hd  = part[0] + part[1] + part[2] + part[3];
        float sg  = 1.f / (1.f + expf(-(hd + b_halt[0])));
        float acc = h0[0] + 2.f * sg;
        int*  wsI = (int*)ws;
        int halted = (acc >= THRESH) ? 1 : 0;
        wsI[4] = halted;
        wsI[5] = 0;                        // s_halt (if halted) is sb0
        wsI[6] = halted ? 0 : 1;           // ponder after step 0
        ws[7]  = acc;
        ws[8]  = acc;                      // last_acc if halted
    }
}

// ---------------- k_rest: rare path, steps 1..15 (persistent + grid barrier) ----
#define RG   256
#define RT   256

__device__ __forceinline__ void grid_barrier(int* cnt, int* gen) {
    __syncthreads();
    if (threadIdx.x == 0) {
        __threadfence();
        int g = __hip_atomic_load(gen, __ATOMIC_RELAXED, __HIP_MEMORY_SCOPE_AGENT);
        int prev = __hip_atomic_fetch_add(cnt, 1, __ATOMIC_ACQ_REL, __HIP_MEMORY_SCOPE_AGENT);
        if (prev == RG - 1) {
            __hip_atomic_store(cnt, 0, __ATOMIC_RELAXED, __HIP_MEMORY_SCOPE_AGENT);
            __hip_atomic_fetch_add(gen, 1, __ATOMIC_RELEASE, __HIP_MEMORY_SCOPE_AGENT);
        } else {
            while (__hip_atomic_load(gen, __ATOMIC_ACQUIRE, __HIP_MEMORY_SCOPE_AGENT) == g)
                __builtin_amdgcn_s_sleep(8);
        }
        __threadfence();
    }
    __syncthreads();
}

__global__ __launch_bounds__(RT) void k_rest(
    const float* __restrict__ x,
    const float* __restrict__ h0,
    const float* __restrict__ W_ih,   const float* __restrict__ b_ih,
    const float* __restrict__ W_hh,   const float* __restrict__ b_hh,
    const float* __restrict__ W_halt, const float* __restrict__ b_halt,
    float* ws)
{
    int* wsI = (int*)ws;
    if (h0[0] >= THRESH) return;     // no steps ran at all
    if (wsI[4]) return;              // halted at step 0 (common case): ~no-op

    float* hdot = ws + 16;
    float* sb0  = ws + 32;
    float* sb1  = ws + 32 + H;

    const int tid = threadIdx.x, bid = blockIdx.x;
    const int wave = tid >> 6, lane = tid & 63;

    __shared__ float xl[H];
    __shared__ float sl[H];
    if (tid == 0) xl[0] = 0.f;       // flag = 0 for all t >= 1
    for (int i = tid; i < H - 1; i += RT) xl[i + 1] = x[i];

    float acc    = ws[7];
    int   ponder = wsI[6];
    const float bh = b_halt[0];
    bool  halted = false;
    int   sel = 0;
    float last_acc = 0.f;

    for (int t = 1; t < NMAX; ++t) {
        const float* scur = (t & 1) ? sb0 : sb1;
        float*       snew = (t & 1) ? sb1 : sb0;

        __syncthreads();
        for (int i = tid; i < H / 4; i += RT)
            ((float4*)sl)[i] = ((const float4*)scur)[i];
        __syncthreads();

        for (int r = 0; r < 4; ++r) {
            const int row = bid * 16 + r * 4 + wave;
            const float4* wih = (const float4*)(W_ih + (size_t)row * H);
            const float4* whh = (const float4*)(W_hh + (size_t)row * H);
            float a0 = 0.f, a1 = 0.f;
            #pragma unroll 4
            for (int k = 0; k < 16; ++k) {
                const int idx = lane + (k << 6);
                float4 wa = wih[idx], wb = whh[idx];
                float4 va = ((const float4*)xl)[idx], vb = ((const float4*)sl)[idx];
                a0 += wa.x*va.x + wa.y*va.y + wa.z*va.z + wa.w*va.w;
                a1 += wb.x*vb.x + wb.y*vb.y + wb.z*vb.z + wb.w*vb.w;
            }
            float a = wave_reduce(a0 + a1);
            if (lane == 0) {
                float sv = tanhf(a + b_ih[row] + b_hh[row]);
                snew[row] = sv;
                atomicAdd(&hdot[t], W_halt[row] * sv);   // rare path: contention OK
            }
        }

        grid_barrier((int*)ws, (int*)ws + 1);

        float hd = ((volatile float*)hdot)[t];
        float sg = 1.f / (1.f + expf(-(hd + bh)));
        acc += 2.f * sg;
        if (acc >= THRESH) { halted = true; last_acc = acc; sel = (t & 1) ? 1 : 0; break; }
        ponder++;
    }

    if (bid == 0 && tid == 0) {
        wsI[4] = halted ? 1 : 0;
        wsI[5] = sel;
        wsI[6] = ponder;
        ws[8]  = last_acc;
    }
}

// ---------------- k_out: output matvec, P=6 pipelined + epilogue ----------------
// 1024 blocks x 256 thr, 4 blocks/CU. 4 rows/block, 1 full row/wave.
#define P1 6
__global__ __launch_bounds__(256, 4) void k_out(
    const float* __restrict__ s0,    const float* __restrict__ y0,
    const float* __restrict__ h0,
    const float* __restrict__ W_out, const float* __restrict__ b_out,
    const float* __restrict__ ws, float* __restrict__ out)
{
    const float h0v = h0[0];
    const int tid = threadIdx.x, bid = blockIdx.x;

    if (h0v >= THRESH) {             // binarize(h0)==1: pass-through
        for (int i = bid * 256 + tid; i < H; i += 1024 * 256) {
            out[i]     = y0[i];
            out[H + i] = s0[i];
        }
        if (bid == 0 && tid == 0) { out[2*H] = 0.f; out[2*H + 1] = h0v - 1.f; }
        return;
    }

    const int* wsI = (const int*)ws;
    if (!wsI[4]) {                   // never halted within NMAX steps
        for (int i = bid * 256 + tid; i < H; i += 1024 * 256) {
            out[i]     = 0.f;
            out[H + i] = 0.f;
        }
        if (bid == 0 && tid == 0) { out[2*H] = (float)wsI[6]; out[2*H + 1] = -1.f; }
        return;
    }

    const float* sfin = ws + 32 + (wsI[5] ? H : 0);
    __shared__ float sl[H];
    {
        const float4* sg = (const float4*)sfin;
        #pragma unroll
        for (int i = 0; i < 4; ++i)
            ((float4*)sl)[tid + (i << 8)] = sg[tid + (i << 8)];
    }
    __syncthreads();

    const int wave = tid >> 6, lane = tid & 63;
    const int row  = bid * 4 + wave;
    const float4* wo = (const float4*)(W_out + (size_t)row * H);
    const float4* sv = (const float4*)sl;

    float4 w[P1];
    #pragma unroll
    for (int p = 0; p < P1; ++p) w[p] = wo[lane + (p << 6)];
    float a0 = 0.f, a1 = 0.f;
    #pragma unroll
    for (int k = 0; k < 16; ++k) {
        const int s = k % P1;
        float4 cw = w[s];
        const int kp = k + P1;
        if (kp < 16) w[s] = wo[lane + (kp << 6)];
        float4 v = sv[lane + (k << 6)];
        a0 += cw.x*v.x + cw.y*v.y;
        a1 += cw.z*v.z + cw.w*v.w;
    }
    float a = wave_reduce(a0 + a1);
    if (lane == 0) {
        out[row]     = a + b_out[row];
        out[H + row] = sl[row];
    }
    if (bid == 0 && tid == 0) {
        out[2*H]     = (float)wsI[6];
        out[2*H + 1] = ws[8] - 1.f;
    }
}

extern "C" void kernel_launch(void* const* d_in, const int* in_sizes, int n_in,
                              void* d_out, int out_size, void* d_ws, size_t ws_size,
                              hipStream_t stream) {
    const float* x      = (const float*)d_in[0];
    const float* s0     = (const float*)d_in[1];
    const float* y0     = (const float*)d_in[2];
    const float* h0     = (const float*)d_in[3];
    const float* W_ih   = (const float*)d_in[4];
    const float* b_ih   = (const float*)d_in[5];
    const float* W_hh   = (const float*)d_in[6];
    const float* b_hh   = (const float*)d_in[7];
    const float* W_halt = (const float*)d_in[8];
    const float* b_halt = (const float*)d_in[9];
    const float* W_out  = (const float*)d_in[10];
    const float* b_out  = (const float*)d_in[11];
    float* out = (float*)d_out;
    float* ws  = (float*)d_ws;   // (32 + 2*4096)*4 B ≈ 33 KB used

    k_prep<<<dim3(16),   dim3(256), 0, stream>>>(x, ws, out);
    k_step0<<<dim3(1024), dim3(256), 0, stream>>>(
        s0, h0, W_ih, b_ih, W_hh, b_hh, W_halt, ws, out);
    k_halt<<<dim3(1),    dim3(256), 0, stream>>>(h0, b_halt, out, ws);
    k_rest<<<dim3(RG),   dim3(RT),  0, stream>>>(
        x, h0, W_ih, b_ih, W_hh, b_hh, W_halt, b_halt, ws);
    k_out<<<dim3(1024),  dim3(256), 0, stream>>>(
        s0, y0, h0, W_out, b_out, ws, out);
}

// Round 7
// 217.026 us; speedup vs baseline: 1.7247x; 1.0341x over previous
//
#include <hip/hip_runtime.h>
#include <math.h>

// ACT skip-RNN, H=O=4096, I=4095 (xin=[flag,x], len 4096).
// R7: oversubscribed single-stream waves + k_halt folded into k_rest.
//   k_prep  : zero ws control words + stage aligned xin into out[H..2H)
//   k_step0 : 4096 blocks x 512; block=row, wave=matrix-quarter (single stream);
//             s1 -> ws sb0, halt partial -> out[row]
//   k_rest  : recomputes step-0 halt decision from partials (all blocks, uniform);
//             rare path steps 1..15 persistent + grid barrier; owns state words
//   k_out   : 2048 blocks x 512; y = W_out@s_halt + b_out, epilogue
// out scratch: [0..H)=hpartials, [H..2H)=xin; both dead before k_out writes.
// ws float layout: [0]=cnt [1]=gen [4]=halted [5]=sel [6]=ponder [8]=last_acc
//   [16..32)=hdot[16] [32..32+H)=sb0 [32+H..32+2H)=sb1   (~33 KB)

#define H      4096
#define NMAX   16
#define THRESH 0.99f         // 1.0 - EPS

__device__ __forceinline__ float wave_reduce(float a) {
    #pragma unroll
    for (int off = 32; off > 0; off >>= 1) a += __shfl_down(a, off);
    return a;
}

// ---------------- k_prep: control-word zero + aligned xin staging ----------------
__global__ __launch_bounds__(256) void k_prep(
    const float* __restrict__ x, float* __restrict__ ws, float* __restrict__ out)
{
    const int i = blockIdx.x * 256 + threadIdx.x;
    if (i < 32) ws[i] = 0.f;               // cnt/gen/halted/sel/ponder/hdot
    if (i == 0) out[H] = 0.f;              // xin[0] flag slot (t==0 flag via W col 0)
    if (i < H - 1) out[H + 1 + i] = x[i];
}

// ---------------- k_step0: step-0 matvec ----------------
// 4096 blocks x 512 thr; block = 1 row; 8 waves: w<4 -> W_ih quarter w,
// w>=4 -> W_hh quarter w-4. Single weight stream per wave, 4 float4/lane
// issued together. Vectors read from global (L2-resident). No LDS staging.
__global__ __launch_bounds__(512, 4) void k_step0(
    const float* __restrict__ s0,     const float* __restrict__ h0,
    const float* __restrict__ W_ih,   const float* __restrict__ b_ih,
    const float* __restrict__ W_hh,   const float* __restrict__ b_hh,
    const float* __restrict__ W_halt,
    float* __restrict__ ws, float* __restrict__ out)
{
    if (h0[0] >= THRESH) return;           // ACT loop never executes

    const int tid  = threadIdx.x, bid = blockIdx.x;
    const int wave = tid >> 6,   lane = tid & 63;
    const int q    = wave & 3,   m    = wave >> 2;
    const int row  = bid;

    const float4* w4 = (const float4*)((m ? W_hh : W_ih) + (size_t)row * H);
    const float4* v4 = (const float4*)(m ? s0 : (out + H));   // xin at out[H..2H)
    const int base = q * 256 + lane;

    float4 w0 = w4[base      ], w1 = w4[base +  64],
           w2 = w4[base + 128], w3 = w4[base + 192];
    float4 v0 = v4[base      ], v1 = v4[base +  64],
           v2 = v4[base + 128], v3 = v4[base + 192];

    float a0 = w0.x*v0.x + w0.y*v0.y + w0.z*v0.z + w0.w*v0.w
             + w2.x*v2.x + w2.y*v2.y + w2.z*v2.z + w2.w*v2.w;
    float a1 = w1.x*v1.x + w1.y*v1.y + w1.z*v1.z + w1.w*v1.w
             + w3.x*v3.x + w3.y*v3.y + w3.z*v3.z + w3.w*v3.w;
    float a = wave_reduce(a0 + a1);

    __shared__ float part[8];
    if (lane == 0) part[wave] = a;
    __syncthreads();
    if (tid == 0) {
        float z = part[0] + part[1] + part[2] + part[3]
                + part[4] + part[5] + part[6] + part[7]
                + b_ih[row] + b_hh[row] + W_ih[(size_t)row * H];  // xin[0]=1
        float s1 = tanhf(z);
        ws[32 + row] = s1;                 // sb0 = s1
        out[row] = W_halt[row] * s1;       // private partial slot
    }
}

// ---------------- k_rest: halt decision + rare path (steps 1..15) ----------------
#define RG   256
#define RT   256

__device__ __forceinline__ void grid_barrier(int* cnt, int* gen) {
    __syncthreads();
    if (threadIdx.x == 0) {
        __threadfence();
        int g = __hip_atomic_load(gen, __ATOMIC_RELAXED, __HIP_MEMORY_SCOPE_AGENT);
        int prev = __hip_atomic_fetch_add(cnt, 1, __ATOMIC_ACQ_REL, __HIP_MEMORY_SCOPE_AGENT);
        if (prev == RG - 1) {
            __hip_atomic_store(cnt, 0, __ATOMIC_RELAXED, __HIP_MEMORY_SCOPE_AGENT);
            __hip_atomic_fetch_add(gen, 1, __ATOMIC_RELEASE, __HIP_MEMORY_SCOPE_AGENT);
        } else {
            while (__hip_atomic_load(gen, __ATOMIC_ACQUIRE, __HIP_MEMORY_SCOPE_AGENT) == g)
                __builtin_amdgcn_s_sleep(8);
        }
        __threadfence();
    }
    __syncthreads();
}

__global__ __launch_bounds__(RT) void k_rest(
    const float* __restrict__ x,
    const float* __restrict__ h0,
    const float* __restrict__ W_ih,   const float* __restrict__ b_ih,
    const float* __restrict__ W_hh,   const float* __restrict__ b_hh,
    const float* __restrict__ W_halt, const float* __restrict__ b_halt,
    const float* __restrict__ hpart,  float* ws)
{
    int* wsI = (int*)ws;
    if (h0[0] >= THRESH) return;     // no steps ran at all

    const int tid = threadIdx.x, bid = blockIdx.x;
    const int wave = tid >> 6, lane = tid & 63;

    // ---- recompute step-0 halt decision from partials (uniform across blocks)
    {
        const float4* p4 = (const float4*)hpart;   // out[0..H) as H/4 float4
        float a = 0.f;
        #pragma unroll
        for (int j = 0; j < 4; ++j) {
            float4 v = p4[tid + (j << 8)];
            a += v.x + v.y + v.z + v.w;
        }
        a = wave_reduce(a);
        __shared__ float pr[4];
        if (lane == 0) pr[wave] = a;
        __syncthreads();
        float hd  = pr[0] + pr[1] + pr[2] + pr[3];
        float sg  = 1.f / (1.f + expf(-(hd + b_halt[0])));
        float acc0 = h0[0] + 2.f * sg;
        if (acc0 >= THRESH) {        // halted at step 0: common case
            if (bid == 0 && tid == 0) {
                wsI[4] = 1; wsI[5] = 0; wsI[6] = 0; ws[8] = acc0;
            }
            return;
        }
        // continue into rare path
        if (bid == 0 && tid == 0) { wsI[4] = 0; }
        __syncthreads();
        // stash acc0 in a register each thread already has:
        pr[0] = acc0;                // reuse LDS to broadcast (uniform anyway)
        __syncthreads();
    }

    float* hdot = ws + 16;
    float* sb0  = ws + 32;
    float* sb1  = ws + 32 + H;

    __shared__ float xl[H];
    __shared__ float sl[H];
    if (tid == 0) xl[0] = 0.f;       // flag = 0 for all t >= 1
    for (int i = tid; i < H - 1; i += RT) xl[i + 1] = x[i];

    // recompute acc0 locally (cheap, uniform): avoids LDS lifetime games
    float acc;
    {
        const float4* p4 = (const float4*)hpart;
        float a = 0.f;
        #pragma unroll
        for (int j = 0; j < 4; ++j) {
            float4 v = p4[tid + (j << 8)];
            a += v.x + v.y + v.z + v.w;
        }
        a = wave_reduce(a);
        __shared__ float pr2[4];
        if (lane == 0) pr2[wave] = a;
        __syncthreads();
        float hd = pr2[0] + pr2[1] + pr2[2] + pr2[3];
        acc = h0[0] + 2.f / (1.f + expf(-(hd + b_halt[0])));
    }
    int   ponder = 1;
    const float bh = b_halt[0];
    bool  halted = false;
    int   sel = 0;
    float last_acc = 0.f;

    for (int t = 1; t < NMAX; ++t) {
        const float* scur = (t & 1) ? sb0 : sb1;
        float*       snew = (t & 1) ? sb1 : sb0;

        __syncthreads();
        for (int i = tid; i < H / 4; i += RT)
            ((float4*)sl)[i] = ((const float4*)scur)[i];
        __syncthreads();

        for (int r = 0; r < 4; ++r) {
            const int row = bid * 16 + r * 4 + wave;
            const float4* wih = (const float4*)(W_ih + (size_t)row * H);
            const float4* whh = (const float4*)(W_hh + (size_t)row * H);
            float a0 = 0.f, a1 = 0.f;
            #pragma unroll 4
            for (int k = 0; k < 16; ++k) {
                const int idx = lane + (k << 6);
                float4 wa = wih[idx], wb = whh[idx];
                float4 va = ((const float4*)xl)[idx], vb = ((const float4*)sl)[idx];
                a0 += wa.x*va.x + wa.y*va.y + wa.z*va.z + wa.w*va.w;
                a1 += wb.x*vb.x + wb.y*vb.y + wb.z*vb.z + wb.w*vb.w;
            }
            float a = wave_reduce(a0 + a1);
            if (lane == 0) {
                float sv = tanhf(a + b_ih[row] + b_hh[row]);
                snew[row] = sv;
                atomicAdd(&hdot[t], W_halt[row] * sv);   // rare path: contention OK
            }
        }

        grid_barrier((int*)ws, (int*)ws + 1);

        float hd = ((volatile float*)hdot)[t];
        float sg = 1.f / (1.f + expf(-(hd + bh)));
        acc += 2.f * sg;
        if (acc >= THRESH) { halted = true; last_acc = acc; sel = (t & 1) ? 1 : 0; break; }
        ponder++;
    }

    if (bid == 0 && tid == 0) {
        wsI[4] = halted ? 1 : 0;
        wsI[5] = sel;
        wsI[6] = ponder;
        ws[8]  = last_acc;
    }
}

// ---------------- k_out: output matvec + epilogue ----------------
// 2048 blocks x 512 thr; block = 2 rows; wave = row-quarter, single stream.
__global__ __launch_bounds__(512, 4) void k_out(
    const float* __restrict__ s0,    const float* __restrict__ y0,
    const float* __restrict__ h0,
    const float* __restrict__ W_out, const float* __restrict__ b_out,
    const float* __restrict__ ws, float* __restrict__ out)
{
    const float h0v = h0[0];
    const int tid = threadIdx.x, bid = blockIdx.x;

    if (h0v >= THRESH) {             // binarize(h0)==1: pass-through
        const int i = bid * 512 + tid;
        if (i < H) { out[i] = y0[i]; out[H + i] = s0[i]; }
        if (i == 0) { out[2*H] = 0.f; out[2*H + 1] = h0v - 1.f; }
        return;
    }

    const int* wsI = (const int*)ws;
    if (!wsI[4]) {                   // never halted within NMAX steps
        const int i = bid * 512 + tid;
        if (i < H) { out[i] = 0.f; out[H + i] = 0.f; }
        if (i == 0) { out[2*H] = (float)wsI[6]; out[2*H + 1] = -1.f; }
        return;
    }

    const float* sfin = ws + 32 + (wsI[5] ? H : 0);
    const int wave = tid >> 6, lane = tid & 63;
    const int row  = bid * 2 + (wave >> 2);
    const int q    = wave & 3;

    const float4* w4 = (const float4*)(W_out + (size_t)row * H);
    const float4* v4 = (const float4*)sfin;
    const int base = q * 256 + lane;

    float4 w0 = w4[base      ], w1 = w4[base +  64],
           w2 = w4[base + 128], w3 = w4[base + 192];
    float4 v0 = v4[base      ], v1 = v4[base +  64],
           v2 = v4[base + 128], v3 = v4[base + 192];

    float a0 = w0.x*v0.x + w0.y*v0.y + w0.z*v0.z + w0.w*v0.w
             + w2.x*v2.x + w2.y*v2.y + w2.z*v2.z + w2.w*v2.w;
    float a1 = w1.x*v1.x + w1.y*v1.y + w1.z*v1.z + w1.w*v1.w
             + w3.x*v3.x + w3.y*v3.y + w3.z*v3.z + w3.w*v3.w;
    float a = wave_reduce(a0 + a1);

    __shared__ float part[8];
    if (lane == 0) part[wave] = a;
    __syncthreads();
    if (tid == 0) {
        const int r0 = bid * 2, r1 = r0 + 1;
        out[r0]     = part[0] + part[1] + part[2] + part[3] + b_out[r0];
        out[r1]     = part[4] + part[5] + part[6] + part[7] + b_out[r1];
        out[H + r0] = sfin[r0];
        out[H + r1] = sfin[r1];
        if (bid == 0) {
            out[2*H]     = (float)wsI[6];
            out[2*H + 1] = ws[8] - 1.f;
        }
    }
}

extern "C" void kernel_launch(void* const* d_in, const int* in_sizes, int n_in,
                              void* d_out, int out_size, void* d_ws, size_t ws_size,
                              hipStream_t stream) {
    const float* x      = (const float*)d_in[0];
    const float* s0     = (const float*)d_in[1];
    const float* y0     = (const float*)d_in[2];
    const float* h0     = (const float*)d_in[3];
    const float* W_ih   = (const float*)d_in[4];
    const float* b_ih   = (const float*)d_in[5];
    const float* W_hh   = (const float*)d_in[6];
    const float* b_hh   = (const float*)d_in[7];
    const float* W_halt = (const float*)d_in[8];
    const float* b_halt = (const float*)d_in[9];
    const float* W_out  = (const float*)d_in[10];
    const float* b_out  = (const float*)d_in[11];
    float* out = (float*)d_out;
    float* ws  = (float*)d_ws;   // (32 + 2*4096)*4 B ≈ 33 KB used

    k_prep<<<dim3(16),   dim3(256), 0, stream>>>(x, ws, out);
    k_step0<<<dim3(4096), dim3(512), 0, stream>>>(
        s0, h0, W_ih, b_ih, W_hh, b_hh, W_halt, ws, out);
    k_rest<<<dim3(RG),   dim3(RT),  0, stream>>>(
        x, h0, W_ih, b_ih, W_hh, b_hh, W_halt, b_halt, out, ws);
    k_out<<<dim3(2048),  dim3(512), 0, stream>>>(
        s0, y0, h0, W_out, b_out, ws, out);
}